// Round 7
// baseline (280.906 us; speedup 1.0000x reference)
//
#include <hip/hip_runtime.h>
#include <hip/hip_bf16.h>

// Spectral_Atten: q,k,v = dwconv3x3(conv1x1(x,W*)); channel-attention per head;
// out = conv1x1(attn@v, Wp).
// R1: split latency-bound fused dwgram -> k_dw + k_gram (554->398us).
// R2: k_mmat 160us @0.37% occupancy -> 48-block LDS-tiled (398->281us).
// R3/R5: FAILED store-pattern fixes (vector stores, XCD swizzle, LDS bank fix)
//   -> conv1 pinned at 1.84TB/s. Invariant: 128B segments at 32KB stride.
// R6: tile-major intermediate layout [b][nt][192][64] -> all q0/k0/v0/v1
//   producer writes and consumer reads are contiguous >=24KB per block.
//   New fused k_dwg (dw+gram+norms, ring-buffered, reg-prefetch) removes
//   192MB of traffic; q,k after dwconv never touch HBM.

using bf16x8 = __attribute__((ext_vector_type(8))) short;
using f32x4  = __attribute__((ext_vector_type(4))) float;
using fvec4  = __attribute__((ext_vector_type(4))) float;

#define NB     8
#define CDIM   192
#define NHEADS 6
#define IMGW   128
#define NPIX   16384
#define DDP    1032   // qd/kd row pitch (16B-aligned rows, bank spread)

__device__ __forceinline__ float b2f(unsigned short u){
  return __uint_as_float(((unsigned int)u) << 16);
}
__device__ __forceinline__ unsigned short f2b(float f){
  unsigned int x = __float_as_uint(f);
  return (unsigned short)((x + 0x7FFFu + ((x >> 16) & 1u)) >> 16);
}
__device__ __forceinline__ float ldT(const void* p, size_t i, int isbf){
  return isbf ? b2f(((const unsigned short*)p)[i]) : ((const float*)p)[i];
}
__device__ __forceinline__ f32x4 MF(bf16x8 a, bf16x8 b, f32x4 c){
  return __builtin_amdgcn_mfma_f32_16x16x32_bf16(a, b, c, 0, 0, 0);
}

// ---- dtype detector (bf16 vs fp32 device buffers)
__global__ void k_detect(const unsigned short* x, int* flag){
  int l = threadIdx.x;
  int cnt = 0;
#pragma unroll
  for (int i = 0; i < 2; ++i){
    unsigned short u = x[(l*2 + i)*2];
    float a = fabsf(b2f(u));
    if (a == 0.f || (a > 1e-4f && a < 20.f)) ++cnt;
  }
  int tot = __popcll(__ballot(cnt >= 1)) + __popcll(__ballot(cnt >= 2));
  if (l == 0) *flag = (tot > 64) ? 1 : 0;
}

// ---- pack Wq,Wk,Wv into stacked bf16 [576][192]
__global__ __launch_bounds__(256) void k_prep(const void* Wq, const void* Wk, const void* Wv,
    unsigned short* Wqkv, const int* flag){
  int i = blockIdx.x*256 + threadIdx.x;
  if (i >= 576*192) return;
  int isbf = *flag;
  int m = i / 192, kk = i % 192;
  int t = m / 192;
  const void* W = (t == 0) ? Wq : (t == 1) ? Wk : Wv;
  Wqkv[i] = f2b(ldT(W, (size_t)(m % 192)*192 + kk, isbf));
}

// ---- fused triple 1x1 conv -> TILE-MAJOR q0/k0/v0 [b][nt][192][64]
__global__ __launch_bounds__(256) void k_conv1(const void* x, const unsigned short* Wqkv,
    unsigned short* q0, unsigned short* k0, unsigned short* v0, const int* flag){
  __shared__ unsigned short Bt[64][200];     // x-tile [px][k^s]
  __shared__ unsigned short outb[192][72];   // epilogue tile [m][px]
  int tid = threadIdx.x;
  int ntr = blockIdx.x, b = blockIdx.y;
  int nt = (ntr & 7)*32 + (ntr >> 3);        // XCD grouping (kept from R5)
  int n0 = nt * 64;
  int isbf = *flag;
  if (isbf){
    const unsigned short* xs = (const unsigned short*)x;
    for (int r = tid; r < 1536; r += 256){
      int k = r >> 3, j8 = (r & 7) * 8;
      int s = (r & 7) << 3;
      bf16x8 v = *(const bf16x8*)(xs + (size_t)(b*CDIM + k)*NPIX + n0 + j8);
      int kx = k ^ s;
#pragma unroll
      for (int i = 0; i < 8; ++i) Bt[j8+i][kx] = (unsigned short)v[i];
    }
  } else {
    const float* xf = (const float*)x;
    for (int r = tid; r < 3072; r += 256){
      int k = r >> 4, j4 = (r & 15) * 4;
      int s = ((j4 >> 3) & 7) << 3;
      fvec4 v = *(const fvec4*)(xf + (size_t)(b*CDIM + k)*NPIX + n0 + j4);
      int kx = k ^ s;
#pragma unroll
      for (int i = 0; i < 4; ++i) Bt[j4+i][kx] = f2b(v[i]);
    }
  }
  __syncthreads();
  int w = tid >> 6, l = tid & 63, lr = l & 15, lk = l >> 4;
#pragma unroll 1
  for (int t = 0; t < 3; ++t){
    f32x4 acc[3][4] = {};
    for (int kc = 0; kc < 6; ++kc){
      bf16x8 af[3];
#pragma unroll
      for (int g = 0; g < 3; ++g)
        af[g] = *(const bf16x8*)(Wqkv + ((size_t)t*CDIM + g*64 + w*16 + lr)*CDIM + kc*32 + lk*8);
#pragma unroll
      for (int nf = 0; nf < 4; ++nf){
        int nrow = nf*16 + lr;
        int s = ((nrow >> 3) & 7) << 3;
        bf16x8 bfv = *(const bf16x8*)(&Bt[nrow][(kc*32 + lk*8) ^ s]);
#pragma unroll
        for (int g = 0; g < 3; ++g) acc[g][nf] = MF(af[g], bfv, acc[g][nf]);
      }
    }
    __syncthreads();
#pragma unroll
    for (int g = 0; g < 3; ++g)
#pragma unroll
      for (int nf = 0; nf < 4; ++nf)
#pragma unroll
        for (int r = 0; r < 4; ++r)
          outb[g*64 + w*16 + lk*4 + r][nf*16 + lr] = f2b(acc[g][nf][r]);
    __syncthreads();
    // TILE-MAJOR contiguous 24KB write
    unsigned short* dstT = ((t == 0) ? q0 : (t == 1) ? k0 : v0)
                         + (size_t)(b*256 + nt)*CDIM*64;
    for (int e = tid; e < 1536; e += 256){
      int m = e >> 3, p8 = (e & 7) * 8;
      *(bf16x8*)(dstT + m*64 + p8) = *(const bf16x8*)(&outb[m][p8]);
    }
  }
}

// ---- fused dwconv3x3 + gram + norms. block=(strip s of 8 rows, head h, b).
// q,k dw'd outputs live only in LDS; v -> v1 (tile-major). Ring-buffered rows
// with register prefetch (load r+2 overlaps dw of r).
__global__ __launch_bounds__(256, 1) void k_dwg(const unsigned short* q0,
    const unsigned short* k0, const unsigned short* v0,
    const void* wqd, const void* wkd, const void* wvd,
    unsigned short* v1, float* Spart, float* Npart, const int* flag){
  __shared__ unsigned short ring[3][32][136];   // 3 rows x 32ch x 128px
  __shared__ unsigned short qd[32*DDP];         // dw'd q (also v transient)
  __shared__ unsigned short kd[32*DDP];         // dw'd k
  __shared__ float S_lds[1024];
  __shared__ float nbuf[2][32];
  int tid = threadIdx.x;
  int s = blockIdx.x, h = blockIdx.y, b = blockIdx.z;
  int isbf = *flag;
  int r0 = s*8;
  for (int e = tid; e < 1024; e += 256) S_lds[e] = 0.f;
  int ch = tid >> 3, p0 = (tid & 7) * 16;       // dw mapping: 8 thr/ch
  int chg = h*32 + ch;
  // staging mapping: 2 chunks/thread
  int sch0 = tid >> 4,      sseg0 = tid & 15;
  int sch1 = (tid+256) >> 4, sseg1 = (tid+256) & 15;
  const int order[3] = {2, 0, 1};               // v first (uses qd slot), q, k
#pragma unroll 1
  for (int tt = 0; tt < 3; ++tt){
    int t = order[tt];
    const unsigned short* src = (t == 0) ? q0 : (t == 1) ? k0 : v0;
    const void* wd = (t == 0) ? wqd : (t == 1) ? wkd : wvd;
    unsigned short* dd = (t == 1) ? kd : qd;
    float w9[9];
#pragma unroll
    for (int e = 0; e < 9; ++e) w9[e] = ldT(wd, (size_t)chg*9 + e, isbf);
    const bf16x8 zv = {0,0,0,0,0,0,0,0};
    auto gload = [&](int r, bf16x8& a, bf16x8& c){
      if (r >= 0 && r < 128){
        int t0 = 2*r + (sseg0 >> 3), t1 = 2*r + (sseg1 >> 3);
        a = *(const bf16x8*)(src + ((size_t)(b*256 + t0)*CDIM + h*32 + sch0)*64 + (sseg0 & 7)*8);
        c = *(const bf16x8*)(src + ((size_t)(b*256 + t1)*CDIM + h*32 + sch1)*64 + (sseg1 & 7)*8);
      } else { a = zv; c = zv; }
    };
    auto dswr = [&](int r, bf16x8 a, bf16x8 c){
      int sl = ((r % 3) + 3) % 3;
      *(bf16x8*)(&ring[sl][sch0][sseg0*8]) = a;
      *(bf16x8*)(&ring[sl][sch1][sseg1*8]) = c;
    };
    bf16x8 pa, pc;
    gload(r0-1, pa, pc); dswr(r0-1, pa, pc);
    gload(r0,   pa, pc); dswr(r0,   pa, pc);
    gload(r0+1, pa, pc);
    __syncthreads();
    float sq = 0.f;
#pragma unroll 1
    for (int rr = 0; rr < 8; ++rr){
      int r = r0 + rr;
      dswr(r+1, pa, pc);
      __syncthreads();
      if (rr < 7) gload(r+2, pa, pc);       // prefetch hides under dw
      // dw row r: thread = (ch, 16-px block at p0)
      float f[3][18];
#pragma unroll
      for (int j = 0; j < 3; ++j){
        int sl = (((r-1+j) % 3) + 3) % 3;
        const unsigned short* rp = &ring[sl][ch][0];
        bf16x8 m0 = *(const bf16x8*)(rp + p0);
        bf16x8 m1 = *(const bf16x8*)(rp + p0 + 8);
        f[j][0]  = (p0 > 0)   ? b2f(rp[p0-1])  : 0.f;
        f[j][17] = (p0 < 112) ? b2f(rp[p0+16]) : 0.f;
#pragma unroll
        for (int i = 0; i < 8; ++i){ f[j][1+i] = b2f((unsigned short)m0[i]);
                                     f[j][9+i] = b2f((unsigned short)m1[i]); }
      }
      bf16x8 o0, o1;
#pragma unroll
      for (int c = 0; c < 16; ++c){
        float a = 0.f;
#pragma unroll
        for (int j = 0; j < 3; ++j)
#pragma unroll
          for (int d = 0; d < 3; ++d)
            a = fmaf(w9[j*3+d], f[j][c+d], a);
        if (t < 2) sq = fmaf(a, a, sq);
        if (c < 8) o0[c] = (short)f2b(a); else o1[c-8] = (short)f2b(a);
      }
      *(bf16x8*)(&dd[ch*DDP + rr*128 + p0])     = o0;
      *(bf16x8*)(&dd[ch*DDP + rr*128 + p0 + 8]) = o1;
      __syncthreads();
    }
    if (t < 2){
      sq += __shfl_xor(sq, 1); sq += __shfl_xor(sq, 2); sq += __shfl_xor(sq, 4);
      if ((tid & 7) == 0) nbuf[t][ch] = sq;
    } else {
      // flush v -> v1 tile-major (contiguous 128B units)
      __syncthreads();
      for (int e = tid; e < 4096; e += 256){
        int c = e >> 7, chunk = e & 127;
        int rr2 = chunk >> 4, px = (chunk & 15) * 8;
        int tile = 2*(r0 + rr2) + (px >> 6);
        *(bf16x8*)(v1 + ((size_t)(b*256 + tile)*CDIM + h*32 + c)*64 + (px & 63))
          = *(const bf16x8*)(&qd[c*DDP + rr2*128 + px]);
      }
      __syncthreads();
    }
  }
  __syncthreads();
  // gram S += qd . kd^T over 1024 px via MFMA
  int w = tid >> 6, l = tid & 63, lr = l & 15, lk = l >> 4;
  f32x4 g4[2][2] = {};
#pragma unroll
  for (int kc = 0; kc < 8; ++kc){
    int px = w*256 + kc*32 + lk*8;
    bf16x8 a0 = *(const bf16x8*)(&qd[lr*DDP + px]);
    bf16x8 a1 = *(const bf16x8*)(&qd[(16+lr)*DDP + px]);
    bf16x8 b0 = *(const bf16x8*)(&kd[lr*DDP + px]);
    bf16x8 b1 = *(const bf16x8*)(&kd[(16+lr)*DDP + px]);
    g4[0][0] = MF(a0, b0, g4[0][0]);
    g4[0][1] = MF(a0, b1, g4[0][1]);
    g4[1][0] = MF(a1, b0, g4[1][0]);
    g4[1][1] = MF(a1, b1, g4[1][1]);
  }
  for (int wv = 0; wv < 4; ++wv){
    if (w == wv){
#pragma unroll
      for (int mi = 0; mi < 2; ++mi)
#pragma unroll
        for (int ni = 0; ni < 2; ++ni)
#pragma unroll
          for (int r = 0; r < 4; ++r)
            S_lds[(mi*16 + lk*4 + r)*32 + ni*16 + lr] += g4[mi][ni][r];
    }
    __syncthreads();
  }
  size_t bidx = ((size_t)(b*NHEADS + h)*16 + s);
  for (int e = tid; e < 1024; e += 256) Spart[bidx*1024 + e] = S_lds[e];
  if (tid < 64){
    int tq = tid >> 5, c32 = tid & 31;
    Npart[((((size_t)b*2 + tq)*NHEADS + h)*32 + c32)*16 + s] = nbuf[tq][c32];
  }
}

// ---- reduce partials, l2norm scaling + rescale, softmax rows
__global__ __launch_bounds__(256) void k_attn(const float* Spart, const float* Npart,
    const void* rescale, float* attnG, const int* flag){
  __shared__ float S[1024];
  __shared__ float rn[64];
  int bh = blockIdx.x, tid = threadIdx.x;
  int b = bh / NHEADS, h = bh % NHEADS;
  int isbf = *flag;
  for (int e = tid; e < 1024; e += 256){
    float a = 0.f;
    for (int st = 0; st < 16; ++st) a += Spart[((size_t)bh*16 + st)*1024 + e];
    S[e] = a;
  }
  if (tid < 64){
    int t = tid >> 5, c32 = tid & 31;
    float a = 0.f;
    for (int st = 0; st < 16; ++st)
      a += Npart[((((size_t)b*2 + t)*NHEADS + h)*32 + c32)*16 + st];
    rn[tid] = 1.f / fmaxf(sqrtf(a), 1e-12f);
  }
  __syncthreads();
  if (tid < 32){
    float sc = ldT(rescale, h, isbf);
    float lo[32], mx = -1e30f;
#pragma unroll
    for (int d = 0; d < 32; ++d){
      lo[d] = S[tid*32 + d] * rn[tid] * rn[32 + d] * sc;
      mx = fmaxf(mx, lo[d]);
    }
    float sum = 0.f;
#pragma unroll
    for (int d = 0; d < 32; ++d){ lo[d] = __expf(lo[d] - mx); sum += lo[d]; }
    float inv = 1.f / sum;
#pragma unroll
    for (int d = 0; d < 32; ++d) attnG[(size_t)bh*1024 + tid*32 + d] = lo[d] * inv;
  }
}

// ---- M[b] = Wp @ blockdiag(attn[b])
__global__ __launch_bounds__(256) void k_mmat(const void* Wp, const float* attnG,
    unsigned short* Mb, const int* flag){
  __shared__ float at[NHEADS*1024];
  __shared__ float wp[32][200];
  int b = blockIdx.x, og = blockIdx.y, tid = threadIdx.x;
  int isbf = *flag;
  for (int e = tid; e < NHEADS*1024; e += 256) at[e] = attnG[(size_t)b*NHEADS*1024 + e];
  for (int e = tid; e < 32*192; e += 256){
    int r = e / 192, cdx = e % 192;
    wp[r][cdx] = ldT(Wp, (size_t)(og*32 + r)*CDIM + cdx, isbf);
  }
  __syncthreads();
  int r = tid >> 3, cg = tid & 7;
#pragma unroll 1
  for (int i = 0; i < 24; ++i){
    int dg = cg*24 + i;
    int hh = dg >> 5, d = dg & 31;
    float a = 0.f;
#pragma unroll
    for (int cc = 0; cc < 32; ++cc)
      a += wp[r][hh*32 + cc] * at[hh*1024 + cc*32 + d];
    Mb[(size_t)b*CDIM*CDIM + (size_t)(og*32 + r)*CDIM + dg] = f2b(a);
  }
}

// ---- final: out[b] = M[b] @ v1[b]; v1 is tile-major
__global__ __launch_bounds__(256) void k_out(const unsigned short* v, const unsigned short* Mb,
    void* out, const int* flag){
  __shared__ unsigned short Bt[64][200];
  __shared__ unsigned short outb[192][72];
  int tid = threadIdx.x;
  int ntr = blockIdx.x, b = blockIdx.y;
  int nt = (ntr & 7)*32 + (ntr >> 3);
  int n0 = nt * 64;
  const unsigned short* vtile = v + (size_t)(b*256 + nt)*CDIM*64;
  for (int r = tid; r < 1536; r += 256){
    int k = r >> 3, j8 = (r & 7) * 8;
    int s = (r & 7) << 3;
    bf16x8 vv = *(const bf16x8*)(vtile + (size_t)k*64 + j8);   // contiguous 24KB tile
    int kx = k ^ s;
#pragma unroll
    for (int i = 0; i < 8; ++i) Bt[j8+i][kx] = (unsigned short)vv[i];
  }
  __syncthreads();
  int w = tid >> 6, l = tid & 63, lr = l & 15, lk = l >> 4;
  const unsigned short* A = Mb + (size_t)b*CDIM*CDIM;
  f32x4 acc[3][4] = {};
  for (int kc = 0; kc < 6; ++kc){
    bf16x8 af[3];
#pragma unroll
    for (int g = 0; g < 3; ++g)
      af[g] = *(const bf16x8*)(A + (size_t)(g*64 + w*16 + lr)*CDIM + kc*32 + lk*8);
#pragma unroll
    for (int nf = 0; nf < 4; ++nf){
      int nrow = nf*16 + lr;
      int s = ((nrow >> 3) & 7) << 3;
      bf16x8 bfv = *(const bf16x8*)(&Bt[nrow][(kc*32 + lk*8) ^ s]);
#pragma unroll
      for (int g = 0; g < 3; ++g) acc[g][nf] = MF(af[g], bfv, acc[g][nf]);
    }
  }
  int isbf = *flag;
  if (isbf){
#pragma unroll
    for (int g = 0; g < 3; ++g)
#pragma unroll
      for (int nf = 0; nf < 4; ++nf)
#pragma unroll
        for (int r = 0; r < 4; ++r)
          outb[g*64 + w*16 + lk*4 + r][nf*16 + lr] = f2b(acc[g][nf][r]);
    __syncthreads();
    unsigned short* dst = (unsigned short*)out + (size_t)b*CDIM*NPIX;
    for (int e = tid; e < 1536; e += 256){
      int m = e >> 3, p8 = (e & 7) * 8;
      *(bf16x8*)(dst + (size_t)m*NPIX + n0 + p8) = *(const bf16x8*)(&outb[m][p8]);
    }
  } else {
#pragma unroll
    for (int g = 0; g < 3; ++g)
#pragma unroll
      for (int nf = 0; nf < 4; ++nf)
#pragma unroll
        for (int r = 0; r < 4; ++r){
          int m = g*64 + w*16 + lk*4 + r;
          ((float*)out)[(size_t)(b*CDIM + m)*NPIX + n0 + nf*16 + lr] = acc[g][nf][r];
        }
  }
}

extern "C" void kernel_launch(void* const* d_in, const int* in_sizes, int n_in,
                              void* d_out, int out_size, void* d_ws, size_t ws_size,
                              hipStream_t stream){
  const void* x   = d_in[0];
  const void* Wq  = d_in[1];
  const void* Wk  = d_in[2];
  const void* Wv  = d_in[3];
  const void* Wqd = d_in[4];
  const void* Wkd = d_in[5];
  const void* Wvd = d_in[6];
  const void* rsc = d_in[7];
  const void* Wp  = d_in[8];

  char* ws = (char*)d_ws;
  size_t o = 0;
  int* flag             = (int*)(ws + o);            o += 256;
  unsigned short* Wqkv  = (unsigned short*)(ws + o); o += (size_t)576*192*2;
  unsigned short* q0    = (unsigned short*)(ws + o); o += (size_t)NB*CDIM*NPIX*2;
  unsigned short* k0    = (unsigned short*)(ws + o); o += (size_t)NB*CDIM*NPIX*2;
  unsigned short* v0    = (unsigned short*)(ws + o); o += (size_t)NB*CDIM*NPIX*2;
  unsigned short* v1    = (unsigned short*)(ws + o); o += (size_t)NB*CDIM*NPIX*2;
  float* Spart          = (float*)(ws + o);          o += (size_t)768*1024*4;
  float* Npart          = (float*)(ws + o);          o += (size_t)NB*2*NHEADS*32*16*4;
  float* attnG          = (float*)(ws + o);          o += (size_t)48*1024*4;
  unsigned short* Mb    = (unsigned short*)(ws + o); o += (size_t)NB*CDIM*CDIM*2;

  k_detect<<<dim3(1), 64, 0, stream>>>((const unsigned short*)x, flag);
  k_prep  <<<dim3(432), 256, 0, stream>>>(Wq, Wk, Wv, Wqkv, flag);
  k_conv1 <<<dim3(256, NB), 256, 0, stream>>>(x, Wqkv, q0, k0, v0, flag);
  k_dwg   <<<dim3(16, NHEADS, NB), 256, 0, stream>>>(q0, k0, v0, Wqd, Wkd, Wvd,
                                                     v1, Spart, Npart, flag);
  k_attn  <<<dim3(48), 256, 0, stream>>>(Spart, Npart, rsc, attnG, flag);
  k_mmat  <<<dim3(NB, 6), 256, 0, stream>>>(Wp, attnG, Mb, flag);
  k_out   <<<dim3(256, NB), 256, 0, stream>>>(v1, Mb, d_out, flag);
}